// Round 3
// baseline (416.828 us; speedup 1.0000x reference)
//
#include <hip/hip_runtime.h>
#include <hip/hip_bf16.h>
#include <math.h>

typedef __bf16 bf16x8 __attribute__((ext_vector_type(8)));
typedef float floatx4 __attribute__((ext_vector_type(4)));
typedef float float4v __attribute__((ext_vector_type(4)));
typedef float float2v __attribute__((ext_vector_type(2)));
typedef unsigned short ushortx4 __attribute__((ext_vector_type(4)));
typedef unsigned short ushortx8 __attribute__((ext_vector_type(8)));

__device__ __forceinline__ unsigned short f2bf(float f) {
    unsigned int u = __builtin_bit_cast(unsigned int, f);
    u += 0x7FFFu + ((u >> 16) & 1u);
    return (unsigned short)(u >> 16);
}
__device__ __forceinline__ float bf2f(unsigned short h) {
    unsigned int u = ((unsigned int)h) << 16;
    return __builtin_bit_cast(float, u);
}

__device__ __forceinline__ void gload_lds16(const void* g, void* l) {
    __builtin_amdgcn_global_load_lds(
        (const __attribute__((address_space(1))) unsigned int*)g,
        (__attribute__((address_space(3))) unsigned int*)l, 16, 0, 0);
}

// ---------------------------------------------------------------------------
// cast: out[i] = bf16(in[i]), 8 elems/thread
// ---------------------------------------------------------------------------
__global__ __launch_bounds__(256) void cast_bf16_kernel(
    const float* __restrict__ in, unsigned short* __restrict__ out, long n8)
{
    long i = (long)blockIdx.x * 256 + threadIdx.x;
    long stride = (long)gridDim.x * 256;
    for (; i < n8; i += stride) {
        float4v a = reinterpret_cast<const float4v*>(in)[2 * i];
        float4v b = reinterpret_cast<const float4v*>(in)[2 * i + 1];
        ushortx8 h;
        #pragma unroll
        for (int q = 0; q < 4; ++q) { h[q] = f2bf(a[q]); h[4 + q] = f2bf(b[q]); }
        reinterpret_cast<ushortx8*>(out)[i] = h;
    }
}

// ---------------------------------------------------------------------------
// prep: W1e[ci*90 + tap*10 + co] = w1[co,ci,di,dj]   (tap = di*3+dj)
//       w23[tap*10 + c10]        = sum_c5 w3[c5] * w2[c5,c10,di,dj]
// ---------------------------------------------------------------------------
__global__ __launch_bounds__(256) void prep_kernel(
    const float* __restrict__ w1, const float* __restrict__ w2,
    const float* __restrict__ w3, float* __restrict__ W1e,
    float* __restrict__ w23)
{
    for (int idx = threadIdx.x; idx < 4590; idx += 256) {
        int ci = idx / 90, rem = idx % 90;
        int tap = rem / 10, co = rem % 10;
        int di = tap / 3, dj = tap % 3;
        W1e[idx] = w1[((co * 51 + ci) * 3 + di) * 3 + dj];
    }
    if (threadIdx.x < 90) {
        int tap = threadIdx.x / 10, c10 = threadIdx.x % 10;
        int di = tap / 3, dj = tap % 3;
        float s = 0.f;
        #pragma unroll
        for (int c5 = 0; c5 < 5; ++c5)
            s = fmaf(w3[c5], w2[((c5 * 10 + c10) * 3 + di) * 3 + dj], s);
        w23[threadIdx.x] = s;
    }
}

// ---------------------------------------------------------------------------
// fp1: Fp1[p][t] = sum_ci freq[p][ci] * W1e[ci][t]   (t = tap*10+co, 90 wide)
// ---------------------------------------------------------------------------
__global__ __launch_bounds__(256) void fp1_kernel(
    const float* __restrict__ freq, const float* __restrict__ W1e,
    float* __restrict__ Fp1)
{
    __shared__ float W1s[4590];
    for (int idx = threadIdx.x; idx < 4590; idx += 256)
        W1s[idx] = W1e[idx];
    __syncthreads();
    int p = blockIdx.x * 256 + threadIdx.x;
    if (p >= 22801) return;
    float2v acc[45];
    #pragma unroll
    for (int t = 0; t < 45; ++t) { acc[t][0] = 0.f; acc[t][1] = 0.f; }
    const float* fr = freq + (size_t)p * 51;
    for (int ci = 0; ci < 51; ++ci) {
        float v = fr[ci];
        const float2v* wrow = reinterpret_cast<const float2v*>(&W1s[ci * 90]);
        #pragma unroll
        for (int t = 0; t < 45; ++t) {
            float2v w = wrow[t];
            acc[t][0] = fmaf(v, w[0], acc[t][0]);
            acc[t][1] = fmaf(v, w[1], acc[t][1]);
        }
    }
    float2v* out = reinterpret_cast<float2v*>(Fp1 + (size_t)p * 90);
    #pragma unroll
    for (int t = 0; t < 45; ++t) out[t] = acc[t];
}

// ---------------------------------------------------------------------------
// gather: h1[b,pix][c10] = sum_{valid taps} Fp1[pair(i',j')][tap*10 + c10]
// ---------------------------------------------------------------------------
__global__ __launch_bounds__(320) void gather_kernel(
    const int* __restrict__ preds, const float* __restrict__ Fp1,
    float* __restrict__ h1)
{
    __shared__ int pb[80];
    const int b = blockIdx.y;
    const int tid = threadIdx.x;
    if (tid < 80) pb[tid] = preds[b * 80 + tid];
    __syncthreads();
    const int i = blockIdx.x * 4 + tid / 80;
    const int j = tid % 80;
    float2v acc[5];
    #pragma unroll
    for (int q = 0; q < 5; ++q) { acc[q][0] = 0.f; acc[q][1] = 0.f; }
    #pragma unroll
    for (int di = 0; di < 3; ++di) {
        int ii = i + di - 1;
        if (ii < 0 || ii >= 80) continue;
        int pi = pb[ii] * 151;
        #pragma unroll
        for (int dj = 0; dj < 3; ++dj) {
            int jj = j + dj - 1;
            if (jj < 0 || jj >= 80) continue;
            const float2v* row = reinterpret_cast<const float2v*>(
                Fp1 + (size_t)(pi + pb[jj]) * 90 + (di * 3 + dj) * 10);
            #pragma unroll
            for (int q = 0; q < 5; ++q) {
                float2v v = row[q];
                acc[q][0] += v[0];
                acc[q][1] += v[1];
            }
        }
    }
    float2v* out = reinterpret_cast<float2v*>(
        h1 + ((size_t)b * 6400 + i * 80 + j) * 10);
    #pragma unroll
    for (int q = 0; q < 5; ++q) out[q] = acc[q];
}

// ---------------------------------------------------------------------------
// conv23: adj[b,i,j] = sigmoid( sum_{taps,c10} w23[tap,c10]*h1[b,nbpix][c10] )
// ---------------------------------------------------------------------------
__global__ __launch_bounds__(320) void conv23_kernel(
    const float* __restrict__ h1, const float* __restrict__ w23g,
    float* __restrict__ adj)
{
    __shared__ float w23s[90];
    const int tid = threadIdx.x;
    if (tid < 90) w23s[tid] = w23g[tid];
    __syncthreads();
    const int b = blockIdx.y;
    const int i = blockIdx.x * 4 + tid / 80;
    const int j = tid % 80;
    float t = 0.f;
    #pragma unroll
    for (int di = 0; di < 3; ++di) {
        int ii = i + di - 1;
        if (ii < 0 || ii >= 80) continue;
        #pragma unroll
        for (int dj = 0; dj < 3; ++dj) {
            int jj = j + dj - 1;
            if (jj < 0 || jj >= 80) continue;
            const float2v* hp = reinterpret_cast<const float2v*>(
                h1 + ((size_t)b * 6400 + ii * 80 + jj) * 10);
            const float* wp = w23s + (di * 3 + dj) * 10;
            #pragma unroll
            for (int q = 0; q < 5; ++q) {
                float2v v = hp[q];
                t = fmaf(v[0], wp[2 * q], t);
                t = fmaf(v[1], wp[2 * q + 1], t);
            }
        }
    }
    adj[(size_t)b * 6400 + i * 80 + j] = 1.0f / (1.0f + __expf(-t));
}

// ---------------------------------------------------------------------------
// degree: deg[b,i] = rsqrt(1 + sum_j adj[b,i,j] + 1e-5)
// ---------------------------------------------------------------------------
__global__ __launch_bounds__(128) void degree_kernel(
    const float* __restrict__ adj, float* __restrict__ deg)
{
    int b = blockIdx.x;
    int i = threadIdx.x;
    if (i >= 80) return;
    const float* row = adj + (size_t)b * 6400 + i * 80;
    float s = 1.0f + 1e-5f;
    for (int jj = 0; jj < 80; ++jj) s += row[jj];
    deg[b * 80 + i] = rsqrtf(s);
}

// ---------------------------------------------------------------------------
// transpose-cast: out[C][R] bf16  <-  in[R][C] f32
// ---------------------------------------------------------------------------
__global__ __launch_bounds__(256) void transpose_cast(
    const float* __restrict__ in, unsigned short* __restrict__ out,
    int R, int C)
{
    __shared__ float t[32][33];
    const int tx = threadIdx.x & 31;
    const int ty = threadIdx.x >> 5;
    const int r0 = blockIdx.y * 32, c0 = blockIdx.x * 32;
    #pragma unroll
    for (int k = 0; k < 4; ++k)
        t[ty + k * 8][tx] = in[(size_t)(r0 + ty + k * 8) * C + c0 + tx];
    __syncthreads();
    #pragma unroll
    for (int k = 0; k < 4; ++k)
        out[(size_t)(c0 + ty + k * 8) * R + r0 + tx] = f2bf(t[tx][ty + k * 8]);
}

// ---------------------------------------------------------------------------
// GEMM: C[M,N] = epilogue(A[M,K] @ Bt[N,K]^T)
//   A: f32 (converted during staging) or bf16; Bt: bf16 row-major [N][K]
//   MODE 0: store relu(x) as bf16;  MODE 1: store relu(x)+res as f32
// 128x128 tile, 4 waves (2x2), 4x4 frags of 16x16x32, BK=32.
// bf16 operands staged via global_load_lds (width 16, linear LDS).
// XCD-chunked block swizzle (grid size must be %8==0).
// ---------------------------------------------------------------------------
template<bool A_BF16, int MODE>
__global__ __launch_bounds__(256) void gemm_mfma(
    const void* __restrict__ Ap, const unsigned short* __restrict__ Bt,
    void* __restrict__ Cp, const float* __restrict__ Rp,
    int M, int N, int K)
{
    constexpr int LDA = A_BF16 ? 32 : 40;
    __shared__ unsigned short Al[128 * LDA];
    __shared__ unsigned short Bl[128 * 32];

    const int tid  = threadIdx.x;
    // XCD-chunked swizzle: hw slot orig runs on XCD orig%8; give each XCD a
    // contiguous chunk of logical tiles so same-bn blocks share per-XCD L2.
    const int nwg  = gridDim.x * gridDim.y;
    const int orig = blockIdx.y * gridDim.x + blockIdx.x;
    const int wg   = (orig & 7) * (nwg >> 3) + (orig >> 3);
    const int bm   = (wg % gridDim.x) * 128;
    const int bn   = (wg / gridDim.x) * 128;
    const int wave = tid >> 6;
    const int lane = tid & 63;
    const int wm   = (wave >> 1) * 64;
    const int wn   = (wave & 1) * 64;
    const int lr   = lane & 15;
    const int lk   = (lane >> 4) * 8;

    floatx4 acc[4][4];
    #pragma unroll
    for (int i = 0; i < 4; ++i)
        #pragma unroll
        for (int j = 0; j < 4; ++j)
            #pragma unroll
            for (int r = 0; r < 4; ++r) acc[i][j][r] = 0.0f;

    for (int k0 = 0; k0 < K; k0 += 32) {
        if (A_BF16) {
            const unsigned short* A = (const unsigned short*)Ap;
            #pragma unroll
            for (int it = 0; it < 2; ++it) {
                int idx = tid + it * 256;
                int r = idx >> 2, kc = (idx & 3) * 8;
                gload_lds16(&A[(size_t)(bm + r) * K + k0 + kc], &Al[idx * 8]);
            }
        } else {
            const float* A = (const float*)Ap;
            #pragma unroll
            for (int it = 0; it < 4; ++it) {
                int idx = tid + it * 256;
                int r = idx >> 3, kc = (idx & 7) * 4;
                float4v v = *reinterpret_cast<const float4v*>(
                    &A[(size_t)(bm + r) * K + k0 + kc]);
                ushortx4 h;
                #pragma unroll
                for (int q = 0; q < 4; ++q) h[q] = f2bf(v[q]);
                *reinterpret_cast<ushortx4*>(&Al[r * 40 + kc]) = h;
            }
        }
        #pragma unroll
        for (int it = 0; it < 2; ++it) {
            int idx = tid + it * 256;
            int r = idx >> 2, kc = (idx & 3) * 8;
            gload_lds16(&Bt[(size_t)(bn + r) * K + k0 + kc], &Bl[idx * 8]);
        }
        __syncthreads();

        bf16x8 af[4], bfv[4];
        #pragma unroll
        for (int mi = 0; mi < 4; ++mi)
            af[mi] = *reinterpret_cast<const bf16x8*>(
                &Al[(wm + mi * 16 + lr) * LDA + lk]);
        #pragma unroll
        for (int ni = 0; ni < 4; ++ni)
            bfv[ni] = *reinterpret_cast<const bf16x8*>(
                &Bl[(wn + ni * 16 + lr) * 32 + lk]);
        #pragma unroll
        for (int mi = 0; mi < 4; ++mi)
            #pragma unroll
            for (int ni = 0; ni < 4; ++ni)
                acc[mi][ni] = __builtin_amdgcn_mfma_f32_16x16x32_bf16(
                    af[mi], bfv[ni], acc[mi][ni], 0, 0, 0);
        __syncthreads();
    }

    #pragma unroll
    for (int mi = 0; mi < 4; ++mi) {
        #pragma unroll
        for (int ni = 0; ni < 4; ++ni) {
            #pragma unroll
            for (int r = 0; r < 4; ++r) {
                int row = bm + wm + mi * 16 + (lane >> 4) * 4 + r;
                int col = bn + wn + ni * 16 + lr;
                float v = fmaxf(acc[mi][ni][r], 0.0f);
                size_t off = (size_t)row * N + col;
                if (MODE == 0) {
                    ((unsigned short*)Cp)[off] = f2bf(v);
                } else {
                    ((float*)Cp)[off] = v + Rp[off];
                }
            }
        }
    }
}

// ---------------------------------------------------------------------------
// laplacian matmul: ofl[b,n,k] = d[n] * sum_m (adj[n,m]+I)*d[m] * u[m,k]
// ---------------------------------------------------------------------------
__global__ __launch_bounds__(256) void laplacian_kernel(
    const float* __restrict__ adj, const float* __restrict__ deg,
    const unsigned short* __restrict__ u_in, unsigned short* __restrict__ ofl)
{
    __shared__ float wl[6400];
    __shared__ unsigned short ul[80 * 256];
    const int b   = blockIdx.y;
    const int kq  = blockIdx.x;
    const int tid = threadIdx.x;
    const int ko  = tid & 31;
    const int ngrp = tid >> 5;

    const float* ab = adj + (size_t)b * 6400;
    const float* db = deg + b * 80;
    for (int idx = tid; idx < 6400; idx += 256) {
        int n = idx / 80;
        int m = idx - n * 80;
        float w = ab[idx] + (n == m ? 1.0f : 0.0f);
        wl[idx] = w * db[m];
    }
    const unsigned short* ub = u_in + (size_t)b * 80 * 1024 + kq * 256;
    #pragma unroll
    for (int it = 0; it < 10; ++it) {
        int idx = tid + it * 256;
        int m   = idx >> 5;
        int c8  = (idx & 31) * 8;
        *reinterpret_cast<ushortx8*>(&ul[m * 256 + c8]) =
            *reinterpret_cast<const ushortx8*>(&ub[(size_t)m * 1024 + c8]);
    }
    __syncthreads();

    float acc[10][8];
    #pragma unroll
    for (int ni = 0; ni < 10; ++ni)
        #pragma unroll
        for (int q = 0; q < 8; ++q) acc[ni][q] = 0.0f;

    for (int m = 0; m < 80; ++m) {
        ushortx8 uv = *reinterpret_cast<const ushortx8*>(&ul[m * 256 + ko * 8]);
        float uf[8];
        #pragma unroll
        for (int q = 0; q < 8; ++q) uf[q] = bf2f(uv[q]);
        #pragma unroll
        for (int ni = 0; ni < 10; ++ni) {
            float wv = wl[(ngrp * 10 + ni) * 80 + m];
            #pragma unroll
            for (int q = 0; q < 8; ++q)
                acc[ni][q] = fmaf(wv, uf[q], acc[ni][q]);
        }
    }
    #pragma unroll
    for (int ni = 0; ni < 10; ++ni) {
        int n = ngrp * 10 + ni;
        float dn = db[n];
        ushortx8 o;
        #pragma unroll
        for (int q = 0; q < 8; ++q) o[q] = f2bf(acc[ni][q] * dn);
        *reinterpret_cast<ushortx8*>(
            &ofl[((size_t)(b * 80 + n)) * 1024 + kq * 256 + ko * 8]) = o;
    }
}

// ---------------------------------------------------------------------------
extern "C" void kernel_launch(void* const* d_in, const int* in_sizes, int n_in,
                              void* d_out, int out_size, void* d_ws, size_t ws_size,
                              hipStream_t stream)
{
    const float* enc   = (const float*)d_in[0];   // [64,80,4096]
    const int*   preds = (const int*)d_in[1];     // [64,80]
    const float* freq  = (const float*)d_in[2];   // [22801,51]
    const float* Wc    = (const float*)d_in[3];   // [4096,1024]
    const float* Wou1  = (const float*)d_in[4];   // [1024,1024]
    const float* Wofc  = (const float*)d_in[5];   // [1024,1024]
    const float* Wdec  = (const float*)d_in[6];   // [1024,4096]
    const float* w1    = (const float*)d_in[7];   // [10,51,3,3]
    const float* w2    = (const float*)d_in[8];   // [5,10,3,3]
    const float* w3    = (const float*)d_in[9];   // [1,5,1,1]

    const int M = 5120;  // 64*80
    // workspace layout (ushort units), with aliasing:
    //   comp | obju | R1(h1 f32 / oflu bf16) | R2(Fp1 f32 / um bf16) |
    //   Wcb | Wou1b | Wofcb | Wdecb | W1e | w23 | adj | deg | encb
    unsigned short* comp  = (unsigned short*)d_ws;          // 5120*1024
    unsigned short* obju  = comp + (size_t)M * 1024;
    unsigned short* r1    = obju + (size_t)M * 1024;
    unsigned short* oflu  = r1;
    float*          h1    = (float*)r1;                     // [64*6400][10] f32
    unsigned short* r2    = r1 + 8192000;
    unsigned short* um    = r2;
    float*          Fp1   = (float*)r2;                     // [22801][90] f32
    unsigned short* Wcb   = r2 + (size_t)M * 1024;          // [1024][4096]
    unsigned short* Wou1b = Wcb + (size_t)1024 * 4096;      // [1024][1024]
    unsigned short* Wofcb = Wou1b + (size_t)1024 * 1024;    // [1024][1024]
    unsigned short* Wdecb = Wofcb + (size_t)1024 * 1024;    // [4096][1024]
    float*          W1e   = (float*)(Wdecb + (size_t)4096 * 1024);
    float*          w23   = W1e + 4590;
    float*          adj   = w23 + 90;                       // [64][80][80]
    float*          deg   = adj + (size_t)64 * 6400;        // [64][80]
    unsigned short* encb  = (unsigned short*)(deg + 5120);  // [5120][4096] bf16
    const size_t need_bytes =
        ((size_t)(encb - comp) + (size_t)M * 4096) * sizeof(unsigned short);
    const bool use_encb = ws_size >= need_bytes;

    // --- weight prep ---
    prep_kernel<<<1, 256, 0, stream>>>(w1, w2, w3, W1e, w23);
    transpose_cast<<<dim3(32, 128), 256, 0, stream>>>(Wc, Wcb, 4096, 1024);
    transpose_cast<<<dim3(32, 32), 256, 0, stream>>>(Wou1, Wou1b, 1024, 1024);
    transpose_cast<<<dim3(32, 32), 256, 0, stream>>>(Wofc, Wofcb, 1024, 1024);
    transpose_cast<<<dim3(128, 32), 256, 0, stream>>>(Wdec, Wdecb, 1024, 4096);

    // --- adjacency chain ---
    fp1_kernel<<<90, 256, 0, stream>>>(freq, W1e, Fp1);
    gather_kernel<<<dim3(20, 64), 320, 0, stream>>>(preds, Fp1, h1);
    conv23_kernel<<<dim3(20, 64), 320, 0, stream>>>(h1, w23, adj);
    degree_kernel<<<64, 128, 0, stream>>>(adj, deg);

    // --- main chain ---
    if (use_encb) {
        cast_bf16_kernel<<<2048, 256, 0, stream>>>(
            enc, encb, (long)M * 4096 / 8);
        gemm_mfma<true, 0><<<dim3(40, 8), 256, 0, stream>>>(
            encb, Wcb, comp, nullptr, M, 1024, 4096);
    } else {
        gemm_mfma<false, 0><<<dim3(40, 8), 256, 0, stream>>>(
            enc, Wcb, comp, nullptr, M, 1024, 4096);
    }
    gemm_mfma<true, 0><<<dim3(40, 8), 256, 0, stream>>>(
        comp, Wou1b, obju, nullptr, M, 1024, 1024);
    laplacian_kernel<<<dim3(4, 64), 256, 0, stream>>>(adj, deg, obju, oflu);
    gemm_mfma<true, 0><<<dim3(40, 8), 256, 0, stream>>>(
        oflu, Wofcb, um, nullptr, M, 1024, 1024);
    gemm_mfma<true, 1><<<dim3(40, 32), 256, 0, stream>>>(
        um, Wdecb, d_out, enc, M, 4096, 1024);
}

// Round 4
// 366.277 us; speedup vs baseline: 1.1380x; 1.1380x over previous
//
#include <hip/hip_runtime.h>
#include <hip/hip_bf16.h>
#include <math.h>

typedef __bf16 bf16x8 __attribute__((ext_vector_type(8)));
typedef float floatx4 __attribute__((ext_vector_type(4)));
typedef float float4v __attribute__((ext_vector_type(4)));
typedef float float2v __attribute__((ext_vector_type(2)));
typedef unsigned short ushortx4 __attribute__((ext_vector_type(4)));
typedef unsigned short ushortx8 __attribute__((ext_vector_type(8)));

__device__ __forceinline__ unsigned short f2bf(float f) {
    unsigned int u = __builtin_bit_cast(unsigned int, f);
    u += 0x7FFFu + ((u >> 16) & 1u);
    return (unsigned short)(u >> 16);
}
__device__ __forceinline__ float bf2f(unsigned short h) {
    unsigned int u = ((unsigned int)h) << 16;
    return __builtin_bit_cast(float, u);
}

__device__ __forceinline__ void gload_lds16(const void* g, void* l) {
    __builtin_amdgcn_global_load_lds(
        (const __attribute__((address_space(1))) unsigned int*)g,
        (__attribute__((address_space(3))) unsigned int*)l, 16, 0, 0);
}

// ---------------------------------------------------------------------------
// cast: out[i] = bf16(in[i]), 8 elems/thread
// ---------------------------------------------------------------------------
__global__ __launch_bounds__(256) void cast_bf16_kernel(
    const float* __restrict__ in, unsigned short* __restrict__ out, long n8)
{
    long i = (long)blockIdx.x * 256 + threadIdx.x;
    long stride = (long)gridDim.x * 256;
    for (; i < n8; i += stride) {
        float4v a = reinterpret_cast<const float4v*>(in)[2 * i];
        float4v b = reinterpret_cast<const float4v*>(in)[2 * i + 1];
        ushortx8 h;
        #pragma unroll
        for (int q = 0; q < 4; ++q) { h[q] = f2bf(a[q]); h[4 + q] = f2bf(b[q]); }
        reinterpret_cast<ushortx8*>(out)[i] = h;
    }
}

// ---------------------------------------------------------------------------
// reduce: out[i] = bf16(relu(p0[i] + p1[i])), 8 elems/thread
// ---------------------------------------------------------------------------
__global__ __launch_bounds__(256) void reduce_relu_kernel(
    const unsigned short* __restrict__ p, unsigned short* __restrict__ out,
    long n8, long half_elems)
{
    long i = (long)blockIdx.x * 256 + threadIdx.x;
    long stride = (long)gridDim.x * 256;
    const ushortx8* p0 = reinterpret_cast<const ushortx8*>(p);
    const ushortx8* p1 = reinterpret_cast<const ushortx8*>(p + half_elems);
    for (; i < n8; i += stride) {
        ushortx8 a = p0[i], b = p1[i];
        ushortx8 h;
        #pragma unroll
        for (int q = 0; q < 8; ++q)
            h[q] = f2bf(fmaxf(bf2f(a[q]) + bf2f(b[q]), 0.0f));
        reinterpret_cast<ushortx8*>(out)[i] = h;
    }
}

// ---------------------------------------------------------------------------
// prep: W1e[ci*90 + tap*10 + co] = w1[co,ci,di,dj]   (tap = di*3+dj)
//       w23[tap*10 + c10]        = sum_c5 w3[c5] * w2[c5,c10,di,dj]
// ---------------------------------------------------------------------------
__global__ __launch_bounds__(256) void prep_kernel(
    const float* __restrict__ w1, const float* __restrict__ w2,
    const float* __restrict__ w3, float* __restrict__ W1e,
    float* __restrict__ w23)
{
    for (int idx = threadIdx.x; idx < 4590; idx += 256) {
        int ci = idx / 90, rem = idx % 90;
        int tap = rem / 10, co = rem % 10;
        int di = tap / 3, dj = tap % 3;
        W1e[idx] = w1[((co * 51 + ci) * 3 + di) * 3 + dj];
    }
    if (threadIdx.x < 90) {
        int tap = threadIdx.x / 10, c10 = threadIdx.x % 10;
        int di = tap / 3, dj = tap % 3;
        float s = 0.f;
        #pragma unroll
        for (int c5 = 0; c5 < 5; ++c5)
            s = fmaf(w3[c5], w2[((c5 * 10 + c10) * 3 + di) * 3 + dj], s);
        w23[threadIdx.x] = s;
    }
}

// ---------------------------------------------------------------------------
// fp1: Fp1[p][t] = sum_ci freq[p][ci] * W1e[ci][t]   (t = tap*10+co, 90 wide)
// ---------------------------------------------------------------------------
__global__ __launch_bounds__(256) void fp1_kernel(
    const float* __restrict__ freq, const float* __restrict__ W1e,
    float* __restrict__ Fp1)
{
    __shared__ float W1s[4590];
    for (int idx = threadIdx.x; idx < 4590; idx += 256)
        W1s[idx] = W1e[idx];
    __syncthreads();
    int p = blockIdx.x * 256 + threadIdx.x;
    if (p >= 22801) return;
    float2v acc[45];
    #pragma unroll
    for (int t = 0; t < 45; ++t) { acc[t][0] = 0.f; acc[t][1] = 0.f; }
    const float* fr = freq + (size_t)p * 51;
    for (int ci = 0; ci < 51; ++ci) {
        float v = fr[ci];
        const float2v* wrow = reinterpret_cast<const float2v*>(&W1s[ci * 90]);
        #pragma unroll
        for (int t = 0; t < 45; ++t) {
            float2v w = wrow[t];
            acc[t][0] = fmaf(v, w[0], acc[t][0]);
            acc[t][1] = fmaf(v, w[1], acc[t][1]);
        }
    }
    float2v* out = reinterpret_cast<float2v*>(Fp1 + (size_t)p * 90);
    #pragma unroll
    for (int t = 0; t < 45; ++t) out[t] = acc[t];
}

// ---------------------------------------------------------------------------
// gather: h1[b,pix][c10] = sum_{valid taps} Fp1[pair(i',j')][tap*10 + c10]
// ---------------------------------------------------------------------------
__global__ __launch_bounds__(320) void gather_kernel(
    const int* __restrict__ preds, const float* __restrict__ Fp1,
    float* __restrict__ h1)
{
    __shared__ int pb[80];
    const int b = blockIdx.y;
    const int tid = threadIdx.x;
    if (tid < 80) pb[tid] = preds[b * 80 + tid];
    __syncthreads();
    const int i = blockIdx.x * 4 + tid / 80;
    const int j = tid % 80;
    float2v acc[5];
    #pragma unroll
    for (int q = 0; q < 5; ++q) { acc[q][0] = 0.f; acc[q][1] = 0.f; }
    #pragma unroll
    for (int di = 0; di < 3; ++di) {
        int ii = i + di - 1;
        if (ii < 0 || ii >= 80) continue;
        int pi = pb[ii] * 151;
        #pragma unroll
        for (int dj = 0; dj < 3; ++dj) {
            int jj = j + dj - 1;
            if (jj < 0 || jj >= 80) continue;
            const float2v* row = reinterpret_cast<const float2v*>(
                Fp1 + (size_t)(pi + pb[jj]) * 90 + (di * 3 + dj) * 10);
            #pragma unroll
            for (int q = 0; q < 5; ++q) {
                float2v v = row[q];
                acc[q][0] += v[0];
                acc[q][1] += v[1];
            }
        }
    }
    float2v* out = reinterpret_cast<float2v*>(
        h1 + ((size_t)b * 6400 + i * 80 + j) * 10);
    #pragma unroll
    for (int q = 0; q < 5; ++q) out[q] = acc[q];
}

// ---------------------------------------------------------------------------
// conv23: adj[b,i,j] = sigmoid( sum_{taps,c10} w23[tap,c10]*h1[b,nbpix][c10] )
// ---------------------------------------------------------------------------
__global__ __launch_bounds__(320) void conv23_kernel(
    const float* __restrict__ h1, const float* __restrict__ w23g,
    float* __restrict__ adj)
{
    __shared__ float w23s[90];
    const int tid = threadIdx.x;
    if (tid < 90) w23s[tid] = w23g[tid];
    __syncthreads();
    const int b = blockIdx.y;
    const int i = blockIdx.x * 4 + tid / 80;
    const int j = tid % 80;
    float t = 0.f;
    #pragma unroll
    for (int di = 0; di < 3; ++di) {
        int ii = i + di - 1;
        if (ii < 0 || ii >= 80) continue;
        #pragma unroll
        for (int dj = 0; dj < 3; ++dj) {
            int jj = j + dj - 1;
            if (jj < 0 || jj >= 80) continue;
            const float2v* hp = reinterpret_cast<const float2v*>(
                h1 + ((size_t)b * 6400 + ii * 80 + jj) * 10);
            const float* wp = w23s + (di * 3 + dj) * 10;
            #pragma unroll
            for (int q = 0; q < 5; ++q) {
                float2v v = hp[q];
                t = fmaf(v[0], wp[2 * q], t);
                t = fmaf(v[1], wp[2 * q + 1], t);
            }
        }
    }
    adj[(size_t)b * 6400 + i * 80 + j] = 1.0f / (1.0f + __expf(-t));
}

// ---------------------------------------------------------------------------
// degree: deg[b,i] = rsqrt(1 + sum_j adj[b,i,j] + 1e-5)
// ---------------------------------------------------------------------------
__global__ __launch_bounds__(128) void degree_kernel(
    const float* __restrict__ adj, float* __restrict__ deg)
{
    int b = blockIdx.x;
    int i = threadIdx.x;
    if (i >= 80) return;
    const float* row = adj + (size_t)b * 6400 + i * 80;
    float s = 1.0f + 1e-5f;
    for (int jj = 0; jj < 80; ++jj) s += row[jj];
    deg[b * 80 + i] = rsqrtf(s);
}

// ---------------------------------------------------------------------------
// transpose-cast: out[C][R] bf16  <-  in[R][C] f32
// ---------------------------------------------------------------------------
__global__ __launch_bounds__(256) void transpose_cast(
    const float* __restrict__ in, unsigned short* __restrict__ out,
    int R, int C)
{
    __shared__ float t[32][33];
    const int tx = threadIdx.x & 31;
    const int ty = threadIdx.x >> 5;
    const int r0 = blockIdx.y * 32, c0 = blockIdx.x * 32;
    #pragma unroll
    for (int k = 0; k < 4; ++k)
        t[ty + k * 8][tx] = in[(size_t)(r0 + ty + k * 8) * C + c0 + tx];
    __syncthreads();
    #pragma unroll
    for (int k = 0; k < 4; ++k)
        out[(size_t)(c0 + ty + k * 8) * R + r0 + tx] = f2bf(t[tx][ty + k * 8]);
}

// ---------------------------------------------------------------------------
// GEMM: C[M,N] = epilogue(A[M,:] @ Bt[N,:]^T) over k-range
//   [blockIdx.z*kh, blockIdx.z*kh + kh), row stride lda for both A and Bt.
//   A: f32 (converted during staging) or bf16; Bt: bf16 row-major [N][lda]
//   MODE 0: store relu(x) bf16; MODE 1: store relu(x)+res f32;
//   MODE 2: store raw x bf16 at Cp + z*M*N (split-K partial)
// 128x128 tile, 4 waves (2x2), 4x4 frags of 16x16x32, BK=32.
// ---------------------------------------------------------------------------
template<bool A_BF16, int MODE>
__global__ __launch_bounds__(256) void gemm_mfma(
    const void* __restrict__ Ap, const unsigned short* __restrict__ Bt,
    void* __restrict__ Cp, const float* __restrict__ Rp,
    int M, int N, int lda, int kh)
{
    constexpr int LDA = A_BF16 ? 32 : 40;
    __shared__ unsigned short Al[128 * LDA];
    __shared__ unsigned short Bl[128 * 32];

    const int tid  = threadIdx.x;
    const int bm   = blockIdx.x * 128;
    const int bn   = blockIdx.y * 128;
    const int zoff = blockIdx.z * kh;
    const int wave = tid >> 6;
    const int lane = tid & 63;
    const int wm   = (wave >> 1) * 64;
    const int wn   = (wave & 1) * 64;
    const int lr   = lane & 15;
    const int lk   = (lane >> 4) * 8;

    floatx4 acc[4][4];
    #pragma unroll
    for (int i = 0; i < 4; ++i)
        #pragma unroll
        for (int j = 0; j < 4; ++j)
            #pragma unroll
            for (int r = 0; r < 4; ++r) acc[i][j][r] = 0.0f;

    for (int k0 = zoff; k0 < zoff + kh; k0 += 32) {
        if (A_BF16) {
            const unsigned short* A = (const unsigned short*)Ap;
            #pragma unroll
            for (int it = 0; it < 2; ++it) {
                int idx = tid + it * 256;
                int r = idx >> 2, kc = (idx & 3) * 8;
                gload_lds16(&A[(size_t)(bm + r) * lda + k0 + kc], &Al[idx * 8]);
            }
        } else {
            const float* A = (const float*)Ap;
            #pragma unroll
            for (int it = 0; it < 4; ++it) {
                int idx = tid + it * 256;
                int r = idx >> 3, kc = (idx & 7) * 4;
                float4v v = *reinterpret_cast<const float4v*>(
                    &A[(size_t)(bm + r) * lda + k0 + kc]);
                ushortx4 h;
                #pragma unroll
                for (int q = 0; q < 4; ++q) h[q] = f2bf(v[q]);
                *reinterpret_cast<ushortx4*>(&Al[r * 40 + kc]) = h;
            }
        }
        #pragma unroll
        for (int it = 0; it < 2; ++it) {
            int idx = tid + it * 256;
            int r = idx >> 2, kc = (idx & 3) * 8;
            gload_lds16(&Bt[(size_t)(bn + r) * lda + k0 + kc], &Bl[idx * 8]);
        }
        __syncthreads();

        bf16x8 af[4], bfv[4];
        #pragma unroll
        for (int mi = 0; mi < 4; ++mi)
            af[mi] = *reinterpret_cast<const bf16x8*>(
                &Al[(wm + mi * 16 + lr) * LDA + lk]);
        #pragma unroll
        for (int ni = 0; ni < 4; ++ni)
            bfv[ni] = *reinterpret_cast<const bf16x8*>(
                &Bl[(wn + ni * 16 + lr) * 32 + lk]);
        #pragma unroll
        for (int mi = 0; mi < 4; ++mi)
            #pragma unroll
            for (int ni = 0; ni < 4; ++ni)
                acc[mi][ni] = __builtin_amdgcn_mfma_f32_16x16x32_bf16(
                    af[mi], bfv[ni], acc[mi][ni], 0, 0, 0);
        __syncthreads();
    }

    #pragma unroll
    for (int mi = 0; mi < 4; ++mi) {
        #pragma unroll
        for (int ni = 0; ni < 4; ++ni) {
            #pragma unroll
            for (int r = 0; r < 4; ++r) {
                int row = bm + wm + mi * 16 + (lane >> 4) * 4 + r;
                int col = bn + wn + ni * 16 + lr;
                size_t off = (size_t)row * N + col;
                if (MODE == 0) {
                    ((unsigned short*)Cp)[off] = f2bf(fmaxf(acc[mi][ni][r], 0.f));
                } else if (MODE == 1) {
                    ((float*)Cp)[off] = fmaxf(acc[mi][ni][r], 0.f) + Rp[off];
                } else {
                    ((unsigned short*)Cp)[(size_t)blockIdx.z * M * N + off] =
                        f2bf(acc[mi][ni][r]);
                }
            }
        }
    }
}

// ---------------------------------------------------------------------------
// laplacian matmul: ofl[b,n,k] = d[n] * sum_m (adj[n,m]+I)*d[m] * u[m,k]
// ---------------------------------------------------------------------------
__global__ __launch_bounds__(256) void laplacian_kernel(
    const float* __restrict__ adj, const float* __restrict__ deg,
    const unsigned short* __restrict__ u_in, unsigned short* __restrict__ ofl)
{
    __shared__ float wl[6400];
    __shared__ unsigned short ul[80 * 256];
    const int b   = blockIdx.y;
    const int kq  = blockIdx.x;
    const int tid = threadIdx.x;
    const int ko  = tid & 31;
    const int ngrp = tid >> 5;

    const float* ab = adj + (size_t)b * 6400;
    const float* db = deg + b * 80;
    for (int idx = tid; idx < 6400; idx += 256) {
        int n = idx / 80;
        int m = idx - n * 80;
        float w = ab[idx] + (n == m ? 1.0f : 0.0f);
        wl[idx] = w * db[m];
    }
    const unsigned short* ub = u_in + (size_t)b * 80 * 1024 + kq * 256;
    #pragma unroll
    for (int it = 0; it < 10; ++it) {
        int idx = tid + it * 256;
        int m   = idx >> 5;
        int c8  = (idx & 31) * 8;
        *reinterpret_cast<ushortx8*>(&ul[m * 256 + c8]) =
            *reinterpret_cast<const ushortx8*>(&ub[(size_t)m * 1024 + c8]);
    }
    __syncthreads();

    float acc[10][8];
    #pragma unroll
    for (int ni = 0; ni < 10; ++ni)
        #pragma unroll
        for (int q = 0; q < 8; ++q) acc[ni][q] = 0.0f;

    for (int m = 0; m < 80; ++m) {
        ushortx8 uv = *reinterpret_cast<const ushortx8*>(&ul[m * 256 + ko * 8]);
        float uf[8];
        #pragma unroll
        for (int q = 0; q < 8; ++q) uf[q] = bf2f(uv[q]);
        #pragma unroll
        for (int ni = 0; ni < 10; ++ni) {
            float wv = wl[(ngrp * 10 + ni) * 80 + m];
            #pragma unroll
            for (int q = 0; q < 8; ++q)
                acc[ni][q] = fmaf(wv, uf[q], acc[ni][q]);
        }
    }
    #pragma unroll
    for (int ni = 0; ni < 10; ++ni) {
        int n = ngrp * 10 + ni;
        float dn = db[n];
        ushortx8 o;
        #pragma unroll
        for (int q = 0; q < 8; ++q) o[q] = f2bf(acc[ni][q] * dn);
        *reinterpret_cast<ushortx8*>(
            &ofl[((size_t)(b * 80 + n)) * 1024 + kq * 256 + ko * 8]) = o;
    }
}

// ---------------------------------------------------------------------------
extern "C" void kernel_launch(void* const* d_in, const int* in_sizes, int n_in,
                              void* d_out, int out_size, void* d_ws, size_t ws_size,
                              hipStream_t stream)
{
    const float* enc   = (const float*)d_in[0];   // [64,80,4096]
    const int*   preds = (const int*)d_in[1];     // [64,80]
    const float* freq  = (const float*)d_in[2];   // [22801,51]
    const float* Wc    = (const float*)d_in[3];   // [4096,1024]
    const float* Wou1  = (const float*)d_in[4];   // [1024,1024]
    const float* Wofc  = (const float*)d_in[5];   // [1024,1024]
    const float* Wdec  = (const float*)d_in[6];   // [1024,4096]
    const float* w1    = (const float*)d_in[7];   // [10,51,3,3]
    const float* w2    = (const float*)d_in[8];   // [5,10,3,3]
    const float* w3    = (const float*)d_in[9];   // [1,5,1,1]

    const int M = 5120;  // 64*80
    // workspace layout (ushort units), with aliasing:
    //   comp | obju | R1(h1 f32 / P0 / oflu) | R2(Fp1 f32 / P1-tail / um) |
    //   Wcb | Wou1b | Wofcb | Wdecb | W1e | w23 | adj | deg | encb
    unsigned short* comp  = (unsigned short*)d_ws;          // 5120*1024
    unsigned short* obju  = comp + (size_t)M * 1024;
    unsigned short* r1    = obju + (size_t)M * 1024;        // 16,384,000 B
    unsigned short* oflu  = r1;
    float*          h1    = (float*)r1;                     // [64*6400][10] f32
    unsigned short* P     = r1;                             // [2][5120][1024] bf16
    unsigned short* r2    = r1 + 8192000;                   // 10,485,760 B
    unsigned short* um    = r2;
    float*          Fp1   = (float*)r2;                     // [22801][90] f32
    unsigned short* Wcb   = r2 + (size_t)M * 1024;          // [1024][4096]
    unsigned short* Wou1b = Wcb + (size_t)1024 * 4096;      // [1024][1024]
    unsigned short* Wofcb = Wou1b + (size_t)1024 * 1024;    // [1024][1024]
    unsigned short* Wdecb = Wofcb + (size_t)1024 * 1024;    // [4096][1024]
    float*          W1e   = (float*)(Wdecb + (size_t)4096 * 1024);
    float*          w23   = W1e + 4590;
    float*          adj   = w23 + 90;                       // [64][80][80]
    float*          deg   = adj + (size_t)64 * 6400;        // [64][80]
    unsigned short* encb  = (unsigned short*)(deg + 5120);  // [5120][4096] bf16
    const size_t need_bytes =
        ((size_t)(encb - comp) + (size_t)M * 4096) * sizeof(unsigned short);
    const bool use_encb = ws_size >= need_bytes;

    // --- weight prep ---
    prep_kernel<<<1, 256, 0, stream>>>(w1, w2, w3, W1e, w23);
    transpose_cast<<<dim3(32, 128), 256, 0, stream>>>(Wc, Wcb, 4096, 1024);
    transpose_cast<<<dim3(32, 32), 256, 0, stream>>>(Wou1, Wou1b, 1024, 1024);
    transpose_cast<<<dim3(32, 32), 256, 0, stream>>>(Wofc, Wofcb, 1024, 1024);
    transpose_cast<<<dim3(128, 32), 256, 0, stream>>>(Wdec, Wdecb, 1024, 4096);

    // --- adjacency chain (h1/Fp1 regions die before P reuses them) ---
    fp1_kernel<<<90, 256, 0, stream>>>(freq, W1e, Fp1);
    gather_kernel<<<dim3(20, 64), 320, 0, stream>>>(preds, Fp1, h1);
    conv23_kernel<<<dim3(20, 64), 320, 0, stream>>>(h1, w23, adj);
    degree_kernel<<<64, 128, 0, stream>>>(adj, deg);

    // --- main chain ---
    if (use_encb) {
        cast_bf16_kernel<<<2048, 256, 0, stream>>>(
            enc, encb, (long)M * 4096 / 8);
        // split-K=2: 640 blocks (~2.5/CU) for occupancy; bf16 partials in P
        gemm_mfma<true, 2><<<dim3(40, 8, 2), 256, 0, stream>>>(
            encb, Wcb, P, nullptr, M, 1024, 4096, 2048);
        reduce_relu_kernel<<<2048, 256, 0, stream>>>(
            P, comp, (long)M * 1024 / 8, (size_t)M * 1024);
    } else {
        gemm_mfma<false, 0><<<dim3(40, 8), 256, 0, stream>>>(
            enc, Wcb, comp, nullptr, M, 1024, 4096, 4096);
    }
    gemm_mfma<true, 0><<<dim3(40, 8), 256, 0, stream>>>(
        comp, Wou1b, obju, nullptr, M, 1024, 1024, 1024);
    laplacian_kernel<<<dim3(4, 64), 256, 0, stream>>>(adj, deg, obju, oflu);
    gemm_mfma<true, 0><<<dim3(40, 8), 256, 0, stream>>>(
        oflu, Wofcb, um, nullptr, M, 1024, 1024, 1024);
    gemm_mfma<true, 1><<<dim3(40, 32), 256, 0, stream>>>(
        um, Wdecb, d_out, enc, M, 4096, 1024, 1024);
}

// Round 5
// 347.091 us; speedup vs baseline: 1.2009x; 1.0553x over previous
//
#include <hip/hip_runtime.h>
#include <hip/hip_bf16.h>
#include <math.h>

typedef __bf16 bf16x8 __attribute__((ext_vector_type(8)));
typedef float floatx4 __attribute__((ext_vector_type(4)));
typedef float float4v __attribute__((ext_vector_type(4)));
typedef float float2v __attribute__((ext_vector_type(2)));
typedef unsigned short ushortx4 __attribute__((ext_vector_type(4)));
typedef unsigned short ushortx8 __attribute__((ext_vector_type(8)));

__device__ __forceinline__ unsigned short f2bf(float f) {
    unsigned int u = __builtin_bit_cast(unsigned int, f);
    u += 0x7FFFu + ((u >> 16) & 1u);
    return (unsigned short)(u >> 16);
}
__device__ __forceinline__ float bf2f(unsigned short h) {
    unsigned int u = ((unsigned int)h) << 16;
    return __builtin_bit_cast(float, u);
}

__device__ __forceinline__ void gload_lds16(const void* g, void* l) {
    __builtin_amdgcn_global_load_lds(
        (const __attribute__((address_space(1))) unsigned int*)g,
        (__attribute__((address_space(3))) unsigned int*)l, 16, 0, 0);
}

// ---------------------------------------------------------------------------
// cast: out[i] = bf16(in[i]), 8 elems/thread
// ---------------------------------------------------------------------------
__global__ __launch_bounds__(256) void cast_bf16_kernel(
    const float* __restrict__ in, unsigned short* __restrict__ out, long n8)
{
    long i = (long)blockIdx.x * 256 + threadIdx.x;
    long stride = (long)gridDim.x * 256;
    for (; i < n8; i += stride) {
        float4v a = reinterpret_cast<const float4v*>(in)[2 * i];
        float4v b = reinterpret_cast<const float4v*>(in)[2 * i + 1];
        ushortx8 h;
        #pragma unroll
        for (int q = 0; q < 4; ++q) { h[q] = f2bf(a[q]); h[4 + q] = f2bf(b[q]); }
        reinterpret_cast<ushortx8*>(out)[i] = h;
    }
}

// ---------------------------------------------------------------------------
// reduce: out[i] = bf16(relu(p0[i] + p1[i])), 8 elems/thread
// ---------------------------------------------------------------------------
__global__ __launch_bounds__(256) void reduce_relu_kernel(
    const unsigned short* __restrict__ p, unsigned short* __restrict__ out,
    long n8, long half_elems)
{
    long i = (long)blockIdx.x * 256 + threadIdx.x;
    long stride = (long)gridDim.x * 256;
    const ushortx8* p0 = reinterpret_cast<const ushortx8*>(p);
    const ushortx8* p1 = reinterpret_cast<const ushortx8*>(p + half_elems);
    for (; i < n8; i += stride) {
        ushortx8 a = p0[i], b = p1[i];
        ushortx8 h;
        #pragma unroll
        for (int q = 0; q < 8; ++q)
            h[q] = f2bf(fmaxf(bf2f(a[q]) + bf2f(b[q]), 0.0f));
        reinterpret_cast<ushortx8*>(out)[i] = h;
    }
}

// ---------------------------------------------------------------------------
// prep: W1e[ci*90 + tap*10 + co] = w1[co,ci,di,dj]   (tap = di*3+dj)
//       w23[tap*10 + c10]        = sum_c5 w3[c5] * w2[c5,c10,di,dj]
// ---------------------------------------------------------------------------
__global__ __launch_bounds__(256) void prep_kernel(
    const float* __restrict__ w1, const float* __restrict__ w2,
    const float* __restrict__ w3, float* __restrict__ W1e,
    float* __restrict__ w23)
{
    for (int idx = threadIdx.x; idx < 4590; idx += 256) {
        int ci = idx / 90, rem = idx % 90;
        int tap = rem / 10, co = rem % 10;
        int di = tap / 3, dj = tap % 3;
        W1e[idx] = w1[((co * 51 + ci) * 3 + di) * 3 + dj];
    }
    if (threadIdx.x < 90) {
        int tap = threadIdx.x / 10, c10 = threadIdx.x % 10;
        int di = tap / 3, dj = tap % 3;
        float s = 0.f;
        #pragma unroll
        for (int c5 = 0; c5 < 5; ++c5)
            s = fmaf(w3[c5], w2[((c5 * 10 + c10) * 3 + di) * 3 + dj], s);
        w23[threadIdx.x] = s;
    }
}

// ---------------------------------------------------------------------------
// fp1: Fp1[p][t] = sum_ci freq[p][ci] * W1e[ci][t]   (t = tap*10+co, 90 wide)
// ---------------------------------------------------------------------------
__global__ __launch_bounds__(256) void fp1_kernel(
    const float* __restrict__ freq, const float* __restrict__ W1e,
    float* __restrict__ Fp1)
{
    __shared__ float W1s[4590];
    for (int idx = threadIdx.x; idx < 4590; idx += 256)
        W1s[idx] = W1e[idx];
    __syncthreads();
    int p = blockIdx.x * 256 + threadIdx.x;
    if (p >= 22801) return;
    float2v acc[45];
    #pragma unroll
    for (int t = 0; t < 45; ++t) { acc[t][0] = 0.f; acc[t][1] = 0.f; }
    const float* fr = freq + (size_t)p * 51;
    for (int ci = 0; ci < 51; ++ci) {
        float v = fr[ci];
        const float2v* wrow = reinterpret_cast<const float2v*>(&W1s[ci * 90]);
        #pragma unroll
        for (int t = 0; t < 45; ++t) {
            float2v w = wrow[t];
            acc[t][0] = fmaf(v, w[0], acc[t][0]);
            acc[t][1] = fmaf(v, w[1], acc[t][1]);
        }
    }
    float2v* out = reinterpret_cast<float2v*>(Fp1 + (size_t)p * 90);
    #pragma unroll
    for (int t = 0; t < 45; ++t) out[t] = acc[t];
}

// ---------------------------------------------------------------------------
// gather: h1[b,pix][c10] = sum_{valid taps} Fp1[pair(i',j')][tap*10 + c10]
// ---------------------------------------------------------------------------
__global__ __launch_bounds__(320) void gather_kernel(
    const int* __restrict__ preds, const float* __restrict__ Fp1,
    float* __restrict__ h1)
{
    __shared__ int pb[80];
    const int b = blockIdx.y;
    const int tid = threadIdx.x;
    if (tid < 80) pb[tid] = preds[b * 80 + tid];
    __syncthreads();
    const int i = blockIdx.x * 4 + tid / 80;
    const int j = tid % 80;
    float2v acc[5];
    #pragma unroll
    for (int q = 0; q < 5; ++q) { acc[q][0] = 0.f; acc[q][1] = 0.f; }
    #pragma unroll
    for (int di = 0; di < 3; ++di) {
        int ii = i + di - 1;
        if (ii < 0 || ii >= 80) continue;
        int pi = pb[ii] * 151;
        #pragma unroll
        for (int dj = 0; dj < 3; ++dj) {
            int jj = j + dj - 1;
            if (jj < 0 || jj >= 80) continue;
            const float2v* row = reinterpret_cast<const float2v*>(
                Fp1 + (size_t)(pi + pb[jj]) * 90 + (di * 3 + dj) * 10);
            #pragma unroll
            for (int q = 0; q < 5; ++q) {
                float2v v = row[q];
                acc[q][0] += v[0];
                acc[q][1] += v[1];
            }
        }
    }
    float2v* out = reinterpret_cast<float2v*>(
        h1 + ((size_t)b * 6400 + i * 80 + j) * 10);
    #pragma unroll
    for (int q = 0; q < 5; ++q) out[q] = acc[q];
}

// ---------------------------------------------------------------------------
// conv23: adj[b,i,j] = sigmoid( sum_{taps,c10} w23[tap,c10]*h1[b,nbpix][c10] )
// ---------------------------------------------------------------------------
__global__ __launch_bounds__(320) void conv23_kernel(
    const float* __restrict__ h1, const float* __restrict__ w23g,
    float* __restrict__ adj)
{
    __shared__ float w23s[90];
    const int tid = threadIdx.x;
    if (tid < 90) w23s[tid] = w23g[tid];
    __syncthreads();
    const int b = blockIdx.y;
    const int i = blockIdx.x * 4 + tid / 80;
    const int j = tid % 80;
    float t = 0.f;
    #pragma unroll
    for (int di = 0; di < 3; ++di) {
        int ii = i + di - 1;
        if (ii < 0 || ii >= 80) continue;
        #pragma unroll
        for (int dj = 0; dj < 3; ++dj) {
            int jj = j + dj - 1;
            if (jj < 0 || jj >= 80) continue;
            const float2v* hp = reinterpret_cast<const float2v*>(
                h1 + ((size_t)b * 6400 + ii * 80 + jj) * 10);
            const float* wp = w23s + (di * 3 + dj) * 10;
            #pragma unroll
            for (int q = 0; q < 5; ++q) {
                float2v v = hp[q];
                t = fmaf(v[0], wp[2 * q], t);
                t = fmaf(v[1], wp[2 * q + 1], t);
            }
        }
    }
    adj[(size_t)b * 6400 + i * 80 + j] = 1.0f / (1.0f + __expf(-t));
}

// ---------------------------------------------------------------------------
// degree: deg[b,i] = rsqrt(1 + sum_j adj[b,i,j] + 1e-5)
// ---------------------------------------------------------------------------
__global__ __launch_bounds__(128) void degree_kernel(
    const float* __restrict__ adj, float* __restrict__ deg)
{
    int b = blockIdx.x;
    int i = threadIdx.x;
    if (i >= 80) return;
    const float* row = adj + (size_t)b * 6400 + i * 80;
    float s = 1.0f + 1e-5f;
    for (int jj = 0; jj < 80; ++jj) s += row[jj];
    deg[b * 80 + i] = rsqrtf(s);
}

// ---------------------------------------------------------------------------
// transpose-cast: out[C][R] bf16  <-  in[R][C] f32
// ---------------------------------------------------------------------------
__global__ __launch_bounds__(256) void transpose_cast(
    const float* __restrict__ in, unsigned short* __restrict__ out,
    int R, int C)
{
    __shared__ float t[32][33];
    const int tx = threadIdx.x & 31;
    const int ty = threadIdx.x >> 5;
    const int r0 = blockIdx.y * 32, c0 = blockIdx.x * 32;
    #pragma unroll
    for (int k = 0; k < 4; ++k)
        t[ty + k * 8][tx] = in[(size_t)(r0 + ty + k * 8) * C + c0 + tx];
    __syncthreads();
    #pragma unroll
    for (int k = 0; k < 4; ++k)
        out[(size_t)(c0 + ty + k * 8) * R + r0 + tx] = f2bf(t[tx][ty + k * 8]);
}

// ---------------------------------------------------------------------------
// GEMM: C[M,N] = epilogue(A[M,:] @ Bt[N,:]^T) over k-range
//   [blockIdx.z*kh, blockIdx.z*kh + kh), row stride lda for both A and Bt.
//   A: f32 (converted during staging) or bf16; Bt: bf16 row-major [N][lda]
//   MODE 0: store relu(x) bf16; MODE 1: store relu(x)+res f32;
//   MODE 2: store raw x bf16 at Cp + z*M*N (split-K partial)
// 128x128 tile, 4 waves (2x2), 4x4 frags of 16x16x32, BK=32.
// 2-phase pipeline (T3 minimum recipe): double-buffered LDS; STAGE(t+1)
// issued BEFORE compute(t); ONE __syncthreads (vmcnt0+barrier) per K-step.
// ---------------------------------------------------------------------------
template<bool A_BF16, int MODE>
__global__ __launch_bounds__(256) void gemm_mfma(
    const void* __restrict__ Ap, const unsigned short* __restrict__ Bt,
    void* __restrict__ Cp, const float* __restrict__ Rp,
    int M, int N, int lda, int kh)
{
    constexpr int LDA = A_BF16 ? 32 : 40;
    __shared__ unsigned short Al[2][128 * LDA];
    __shared__ unsigned short Bl[2][128 * 32];

    const int tid  = threadIdx.x;
    const int bm   = blockIdx.x * 128;
    const int bn   = blockIdx.y * 128;
    const int zoff = blockIdx.z * kh;
    const int wave = tid >> 6;
    const int lane = tid & 63;
    const int wm   = (wave >> 1) * 64;
    const int wn   = (wave & 1) * 64;
    const int lr   = lane & 15;
    const int lk   = (lane >> 4) * 8;

    floatx4 acc[4][4];
    #pragma unroll
    for (int i = 0; i < 4; ++i)
        #pragma unroll
        for (int j = 0; j < 4; ++j)
            #pragma unroll
            for (int r = 0; r < 4; ++r) acc[i][j][r] = 0.0f;

    auto stage = [&](int buf, int k0) {
        if constexpr (A_BF16) {
            const unsigned short* A = (const unsigned short*)Ap;
            #pragma unroll
            for (int it = 0; it < 2; ++it) {
                int idx = tid + it * 256;
                int r = idx >> 2, kc = (idx & 3) * 8;
                gload_lds16(&A[(size_t)(bm + r) * lda + k0 + kc],
                            &Al[buf][idx * 8]);
            }
        } else {
            const float* A = (const float*)Ap;
            #pragma unroll
            for (int it = 0; it < 4; ++it) {
                int idx = tid + it * 256;
                int r = idx >> 3, kc = (idx & 7) * 4;
                float4v v = *reinterpret_cast<const float4v*>(
                    &A[(size_t)(bm + r) * lda + k0 + kc]);
                ushortx4 h;
                #pragma unroll
                for (int q = 0; q < 4; ++q) h[q] = f2bf(v[q]);
                *reinterpret_cast<ushortx4*>(&Al[buf][r * 40 + kc]) = h;
            }
        }
        #pragma unroll
        for (int it = 0; it < 2; ++it) {
            int idx = tid + it * 256;
            int r = idx >> 2, kc = (idx & 3) * 8;
            gload_lds16(&Bt[(size_t)(bn + r) * lda + k0 + kc],
                        &Bl[buf][idx * 8]);
        }
    };

    // prologue: fill buffer 0
    stage(0, zoff);
    __syncthreads();

    const int nt = kh >> 5;
    int cur = 0;
    for (int t = 0; t < nt; ++t) {
        if (t + 1 < nt) stage(cur ^ 1, zoff + ((t + 1) << 5));

        bf16x8 af[4], bfv[4];
        #pragma unroll
        for (int mi = 0; mi < 4; ++mi)
            af[mi] = *reinterpret_cast<const bf16x8*>(
                &Al[cur][(wm + mi * 16 + lr) * LDA + lk]);
        #pragma unroll
        for (int ni = 0; ni < 4; ++ni)
            bfv[ni] = *reinterpret_cast<const bf16x8*>(
                &Bl[cur][(wn + ni * 16 + lr) * 32 + lk]);
        #pragma unroll
        for (int mi = 0; mi < 4; ++mi)
            #pragma unroll
            for (int ni = 0; ni < 4; ++ni)
                acc[mi][ni] = __builtin_amdgcn_mfma_f32_16x16x32_bf16(
                    af[mi], bfv[ni], acc[mi][ni], 0, 0, 0);

        __syncthreads();   // drains this iter's stage (vmcnt0) + barrier
        cur ^= 1;
    }

    #pragma unroll
    for (int mi = 0; mi < 4; ++mi) {
        #pragma unroll
        for (int ni = 0; ni < 4; ++ni) {
            #pragma unroll
            for (int r = 0; r < 4; ++r) {
                int row = bm + wm + mi * 16 + (lane >> 4) * 4 + r;
                int col = bn + wn + ni * 16 + lr;
                size_t off = (size_t)row * N + col;
                if (MODE == 0) {
                    ((unsigned short*)Cp)[off] = f2bf(fmaxf(acc[mi][ni][r], 0.f));
                } else if (MODE == 1) {
                    ((float*)Cp)[off] = fmaxf(acc[mi][ni][r], 0.f) + Rp[off];
                } else {
                    ((unsigned short*)Cp)[(size_t)blockIdx.z * M * N + off] =
                        f2bf(acc[mi][ni][r]);
                }
            }
        }
    }
}

// ---------------------------------------------------------------------------
// laplacian matmul: ofl[b,n,k] = d[n] * sum_m (adj[n,m]+I)*d[m] * u[m,k]
// ---------------------------------------------------------------------------
__global__ __launch_bounds__(256) void laplacian_kernel(
    const float* __restrict__ adj, const float* __restrict__ deg,
    const unsigned short* __restrict__ u_in, unsigned short* __restrict__ ofl)
{
    __shared__ float wl[6400];
    __shared__ unsigned short ul[80 * 256];
    const int b   = blockIdx.y;
    const int kq  = blockIdx.x;
    const int tid = threadIdx.x;
    const int ko  = tid & 31;
    const int ngrp = tid >> 5;

    const float* ab = adj + (size_t)b * 6400;
    const float* db = deg + b * 80;
    for (int idx = tid; idx < 6400; idx += 256) {
        int n = idx / 80;
        int m = idx - n * 80;
        float w = ab[idx] + (n == m ? 1.0f : 0.0f);
        wl[idx] = w * db[m];
    }
    const unsigned short* ub = u_in + (size_t)b * 80 * 1024 + kq * 256;
    #pragma unroll
    for (int it = 0; it < 10; ++it) {
        int idx = tid + it * 256;
        int m   = idx >> 5;
        int c8  = (idx & 31) * 8;
        *reinterpret_cast<ushortx8*>(&ul[m * 256 + c8]) =
            *reinterpret_cast<const ushortx8*>(&ub[(size_t)m * 1024 + c8]);
    }
    __syncthreads();

    float acc[10][8];
    #pragma unroll
    for (int ni = 0; ni < 10; ++ni)
        #pragma unroll
        for (int q = 0; q < 8; ++q) acc[ni][q] = 0.0f;

    for (int m = 0; m < 80; ++m) {
        ushortx8 uv = *reinterpret_cast<const ushortx8*>(&ul[m * 256 + ko * 8]);
        float uf[8];
        #pragma unroll
        for (int q = 0; q < 8; ++q) uf[q] = bf2f(uv[q]);
        #pragma unroll
        for (int ni = 0; ni < 10; ++ni) {
            float wv = wl[(ngrp * 10 + ni) * 80 + m];
            #pragma unroll
            for (int q = 0; q < 8; ++q)
                acc[ni][q] = fmaf(wv, uf[q], acc[ni][q]);
        }
    }
    #pragma unroll
    for (int ni = 0; ni < 10; ++ni) {
        int n = ngrp * 10 + ni;
        float dn = db[n];
        ushortx8 o;
        #pragma unroll
        for (int q = 0; q < 8; ++q) o[q] = f2bf(acc[ni][q] * dn);
        *reinterpret_cast<ushortx8*>(
            &ofl[((size_t)(b * 80 + n)) * 1024 + kq * 256 + ko * 8]) = o;
    }
}

// ---------------------------------------------------------------------------
extern "C" void kernel_launch(void* const* d_in, const int* in_sizes, int n_in,
                              void* d_out, int out_size, void* d_ws, size_t ws_size,
                              hipStream_t stream)
{
    const float* enc   = (const float*)d_in[0];   // [64,80,4096]
    const int*   preds = (const int*)d_in[1];     // [64,80]
    const float* freq  = (const float*)d_in[2];   // [22801,51]
    const float* Wc    = (const float*)d_in[3];   // [4096,1024]
    const float* Wou1  = (const float*)d_in[4];   // [1024,1024]
    const float* Wofc  = (const float*)d_in[5];   // [1024,1024]
    const float* Wdec  = (const float*)d_in[6];   // [1024,4096]
    const float* w1    = (const float*)d_in[7];   // [10,51,3,3]
    const float* w2    = (const float*)d_in[8];   // [5,10,3,3]
    const float* w3    = (const float*)d_in[9];   // [1,5,1,1]

    const int M = 5120;  // 64*80
    // workspace layout (ushort units), with aliasing:
    //   comp | obju | R1(h1 f32 / P0 / oflu) | R2(Fp1 f32 / P1-tail / um) |
    //   Wcb | Wou1b | Wofcb | Wdecb | W1e | w23 | adj | deg | encb
    unsigned short* comp  = (unsigned short*)d_ws;          // 5120*1024
    unsigned short* obju  = comp + (size_t)M * 1024;
    unsigned short* r1    = obju + (size_t)M * 1024;        // 16,384,000 B
    unsigned short* oflu  = r1;
    float*          h1    = (float*)r1;                     // [64*6400][10] f32
    unsigned short* P     = r1;                             // [2][5120][1024] bf16
    unsigned short* r2    = r1 + 8192000;                   // 10,485,760 B
    unsigned short* um    = r2;
    float*          Fp1   = (float*)r2;                     // [22801][90] f32
    unsigned short* Wcb   = r2 + (size_t)M * 1024;          // [1024][4096]
    unsigned short* Wou1b = Wcb + (size_t)1024 * 4096;      // [1024][1024]
    unsigned short* Wofcb = Wou1b + (size_t)1024 * 1024;    // [1024][1024]
    unsigned short* Wdecb = Wofcb + (size_t)1024 * 1024;    // [4096][1024]
    float*          W1e   = (float*)(Wdecb + (size_t)4096 * 1024);
    float*          w23   = W1e + 4590;
    float*          adj   = w23 + 90;                       // [64][80][80]
    float*          deg   = adj + (size_t)64 * 6400;        // [64][80]
    unsigned short* encb  = (unsigned short*)(deg + 5120);  // [5120][4096] bf16
    const size_t need_bytes =
        ((size_t)(encb - comp) + (size_t)M * 4096) * sizeof(unsigned short);
    const bool use_encb = ws_size >= need_bytes;

    // --- weight prep ---
    prep_kernel<<<1, 256, 0, stream>>>(w1, w2, w3, W1e, w23);
    transpose_cast<<<dim3(32, 128), 256, 0, stream>>>(Wc, Wcb, 4096, 1024);
    transpose_cast<<<dim3(32, 32), 256, 0, stream>>>(Wou1, Wou1b, 1024, 1024);
    transpose_cast<<<dim3(32, 32), 256, 0, stream>>>(Wofc, Wofcb, 1024, 1024);
    transpose_cast<<<dim3(128, 32), 256, 0, stream>>>(Wdec, Wdecb, 1024, 4096);

    // --- adjacency chain (h1/Fp1 regions die before P reuses them) ---
    fp1_kernel<<<90, 256, 0, stream>>>(freq, W1e, Fp1);
    gather_kernel<<<dim3(20, 64), 320, 0, stream>>>(preds, Fp1, h1);
    conv23_kernel<<<dim3(20, 64), 320, 0, stream>>>(h1, w23, adj);
    degree_kernel<<<64, 128, 0, stream>>>(adj, deg);

    // --- main chain ---
    if (use_encb) {
        cast_bf16_kernel<<<2048, 256, 0, stream>>>(
            enc, encb, (long)M * 4096 / 8);
        // split-K=2: 640 blocks (~2.5/CU) for occupancy; bf16 partials in P
        gemm_mfma<true, 2><<<dim3(40, 8, 2), 256, 0, stream>>>(
            encb, Wcb, P, nullptr, M, 1024, 4096, 2048);
        reduce_relu_kernel<<<2048, 256, 0, stream>>>(
            P, comp, (long)M * 1024 / 8, (size_t)M * 1024);
    } else {
        gemm_mfma<false, 0><<<dim3(40, 8), 256, 0, stream>>>(
            enc, Wcb, comp, nullptr, M, 1024, 4096, 4096);
    }
    gemm_mfma<true, 0><<<dim3(40, 8), 256, 0, stream>>>(
        comp, Wou1b, obju, nullptr, M, 1024, 1024, 1024);
    laplacian_kernel<<<dim3(4, 64), 256, 0, stream>>>(adj, deg, obju, oflu);
    gemm_mfma<true, 0><<<dim3(40, 8), 256, 0, stream>>>(
        oflu, Wofcb, um, nullptr, M, 1024, 1024, 1024);
    gemm_mfma<true, 1><<<dim3(40, 32), 256, 0, stream>>>(
        um, Wdecb, d_out, enc, M, 4096, 1024, 1024);
}